// Round 1
// baseline (664.321 us; speedup 1.0000x reference)
//
#include <hip/hip_runtime.h>
#include <math.h>

#define VOCN 50257
#define OUTD 512
#define HIDD 64
#define CURD 16
#define BB   32
#define SS   4096
#define NCH  256      // SS / CURD
#define KDIM 80       // HIDD + CURD
#define LNEPS 1e-5f

// ---------------------------------------------------------------------------
// Kernel 1: per (chunk, batch): emb gather -> q,k,v -> softmax attn -> LN
// Writes watch into combined[row][0:16].  8192 blocks x 256 threads.
// Thread (i,j) owns element (row i, col j) of the 16x16 tile.
// ---------------------------------------------------------------------------
__global__ __launch_bounds__(256) void attn_kernel(
    const int* __restrict__ x, const float* __restrict__ emb,
    const float* __restrict__ Wq, const float* __restrict__ bq,
    const float* __restrict__ Wk, const float* __restrict__ bk,
    const float* __restrict__ Wv, const float* __restrict__ bv,
    const float* __restrict__ g_lim, const float* __restrict__ b_lim,
    float* __restrict__ combined)
{
    const int blk = blockIdx.x;          // t*32 + b
    const int t   = blk >> 5;
    const int b   = blk & 31;
    const int tid = threadIdx.x;
    const int i   = tid >> 4;            // 0..15 row
    const int j   = tid & 15;            // 0..15 col

    __shared__ int   s_ids[16];
    __shared__ float s_wq[16][16], s_wk[16][16], s_wv[16][16];
    __shared__ float s_read[16][17];
    __shared__ float s_q[16][17], s_k[16][17], s_v[16][17], s_p[16][17];

    if (tid < 16) s_ids[tid] = x[b * SS + t * CURD + tid];
    s_wq[i][j] = Wq[tid];
    s_wk[i][j] = Wk[tid];
    s_wv[i][j] = Wv[tid];
    __syncthreads();

    s_read[i][j] = emb[(size_t)s_ids[i] * CURD + j];
    __syncthreads();

    float q = bq[j], k = bk[j], v = bv[j];
    #pragma unroll
    for (int kk = 0; kk < 16; ++kk) {
        float r = s_read[i][kk];
        q = fmaf(r, s_wq[kk][j], q);
        k = fmaf(r, s_wk[kk][j], k);
        v = fmaf(r, s_wv[kk][j], v);
    }
    s_q[i][j] = q; s_k[i][j] = k; s_v[i][j] = v;
    __syncthreads();

    // scores[i][j] = dot(q_i, k_j) * 1/sqrt(16)
    float sc = 0.f;
    #pragma unroll
    for (int kk = 0; kk < 16; ++kk) sc = fmaf(s_q[i][kk], s_k[j][kk], sc);
    sc *= 0.25f;

    // softmax over j: lanes i*16+j, groups of 16 aligned inside the wave
    float mx = sc;
    #pragma unroll
    for (int off = 8; off; off >>= 1) mx = fmaxf(mx, __shfl_xor(mx, off, 16));
    float p = expf(sc - mx);
    float ps = p;
    #pragma unroll
    for (int off = 8; off; off >>= 1) ps += __shfl_xor(ps, off, 16);
    p /= ps;
    s_p[i][j] = p;
    __syncthreads();

    float w = 0.f;
    #pragma unroll
    for (int kk = 0; kk < 16; ++kk) w = fmaf(s_p[i][kk], s_v[kk][j], w);

    // LayerNorm over j (16)
    float m = w;
    #pragma unroll
    for (int off = 8; off; off >>= 1) m += __shfl_xor(m, off, 16);
    m *= (1.f / 16.f);
    float d = w - m;
    float var = d * d;
    #pragma unroll
    for (int off = 8; off; off >>= 1) var += __shfl_xor(var, off, 16);
    var *= (1.f / 16.f);
    float wn = d * rsqrtf(var + LNEPS) * g_lim[j] + b_lim[j];

    combined[((size_t)blk * CURD + i) * KDIM + j] = wn;
}

// ---------------------------------------------------------------------------
// Kernel 2: 512 independent chains (b, r), one wave64 per chain.
// lane c holds sus[c]; per step: h = [watch, sus] @ Ws + bs; gelu; LN(wave).
// Writes the PRE-update state sus_t into combined[row][16:80].
// ---------------------------------------------------------------------------
__global__ __launch_bounds__(64) void rec_kernel(
    const float* __restrict__ Ws, const float* __restrict__ bs,
    const float* __restrict__ g_doubt, const float* __restrict__ b_doubt,
    float* __restrict__ combined)
{
    const int chain = blockIdx.x;       // b*16 + r
    const int b = chain >> 4;
    const int r = chain & 15;
    const int c = threadIdx.x;          // 0..63

    __shared__ float s_watch[16];
    __shared__ float s_sus[2][64];

    // per-lane weight columns (registers)
    float Wsw[16], Wss[64];
    #pragma unroll
    for (int jj = 0; jj < 16; ++jj) Wsw[jj] = Ws[jj * HIDD + c];
    #pragma unroll
    for (int jj = 0; jj < 64; ++jj) Wss[jj] = Ws[(16 + jj) * HIDD + c];
    const float bsc = bs[c];
    const float gd  = g_doubt[c];
    const float bdo = b_doubt[c];

    float sv = 0.f;                 // my sus element (state entering chunk t)
    s_sus[0][c] = 0.f;
    int p = 0;

    // prefetch watch row for t=0
    float wv = (c < 16) ? combined[(((size_t)0 * BB + b) * CURD + r) * KDIM + c] : 0.f;

    for (int t = 0; t < NCH; ++t) {
        const size_t rowoff = (((size_t)t * BB + b) * CURD + r) * (size_t)KDIM;
        if (c < 16) s_watch[c] = wv;
        __syncthreads();   // covers s_watch write vs prev-iter reads ordering too

        // store pre-update state for kernel 3
        combined[rowoff + 16 + c] = sv;

        // prefetch next chunk's watch row (hide global latency under compute)
        float wv_next = 0.f;
        if (t + 1 < NCH && c < 16)
            wv_next = combined[(((size_t)(t + 1) * BB + b) * CURD + r) * KDIM + c];

        // h = bs + watch @ Ws[0:16] + sus @ Ws[16:80]   (4 partial accumulators)
        float h0 = bsc, h1 = 0.f, h2 = 0.f, h3 = 0.f;
        const float4* wp = (const float4*)(&s_watch[0]);
        {
            float4 a0 = wp[0], a1 = wp[1], a2 = wp[2], a3 = wp[3];
            h0 = fmaf(a0.x, Wsw[0],  h0); h1 = fmaf(a0.y, Wsw[1],  h1);
            h2 = fmaf(a0.z, Wsw[2],  h2); h3 = fmaf(a0.w, Wsw[3],  h3);
            h0 = fmaf(a1.x, Wsw[4],  h0); h1 = fmaf(a1.y, Wsw[5],  h1);
            h2 = fmaf(a1.z, Wsw[6],  h2); h3 = fmaf(a1.w, Wsw[7],  h3);
            h0 = fmaf(a2.x, Wsw[8],  h0); h1 = fmaf(a2.y, Wsw[9],  h1);
            h2 = fmaf(a2.z, Wsw[10], h2); h3 = fmaf(a2.w, Wsw[11], h3);
            h0 = fmaf(a3.x, Wsw[12], h0); h1 = fmaf(a3.y, Wsw[13], h1);
            h2 = fmaf(a3.z, Wsw[14], h2); h3 = fmaf(a3.w, Wsw[15], h3);
        }
        const float4* sp = (const float4*)(&s_sus[p][0]);
        #pragma unroll
        for (int j4 = 0; j4 < 16; ++j4) {
            float4 a = sp[j4];
            h0 = fmaf(a.x, Wss[4*j4+0], h0);
            h1 = fmaf(a.y, Wss[4*j4+1], h1);
            h2 = fmaf(a.z, Wss[4*j4+2], h2);
            h3 = fmaf(a.w, Wss[4*j4+3], h3);
        }
        float h = (h0 + h1) + (h2 + h3);

        // exact gelu
        float g = 0.5f * h * (1.f + erff(h * 0.70710678118654752f));

        // LayerNorm across the wave (64 lanes)
        float s1 = g, s2 = g * g;
        #pragma unroll
        for (int off = 32; off; off >>= 1) {
            s1 += __shfl_xor(s1, off, 64);
            s2 += __shfl_xor(s2, off, 64);
        }
        float m   = s1 * (1.f / 64.f);
        float var = s2 * (1.f / 64.f) - m * m;
        sv = (g - m) * rsqrtf(var + LNEPS) * gd + bdo;

        __syncthreads();   // all reads of s_sus[p]/s_watch done before overwrite
        s_sus[1 - p][c] = sv;
        p ^= 1;
        wv = wv_next;
    }
}

// ---------------------------------------------------------------------------
// Kernel 3: out = LN(combined @ Wd + bd) * g_check + b_check
// M=131072, K=80, N=512.  Block: 32 rows x 512 cols, 256 threads,
// thread c owns cols {c, c+256} for all 32 rows (64 fp32 accumulators).
// ---------------------------------------------------------------------------
#define R3 32
__global__ __launch_bounds__(256) void out_kernel(
    const float* __restrict__ combined, const float* __restrict__ Wd,
    const float* __restrict__ bd, const float* __restrict__ g_check,
    const float* __restrict__ b_check, float* __restrict__ out)
{
    __shared__ float At[R3][84];        // 84*4B = 336B rows: 16B-aligned
    __shared__ float s_red[R3][4][2];

    const int tid = threadIdx.x;
    const size_t rowbase = (size_t)blockIdx.x * R3;

    // stage 32x80 A-tile (rows are 320B -> float4-clean)
    const float4* src4 = (const float4*)(combined + rowbase * KDIM);
    for (int idx = tid; idx < R3 * 20; idx += 256) {
        float4 vv = src4[idx];
        int rr = idx / 20, kk4 = idx % 20;
        *(float4*)&At[rr][kk4 * 4] = vv;
    }
    __syncthreads();

    const int c = tid;
    float acc0[R3], acc1[R3];
    const float bd0 = bd[c], bd1 = bd[c + 256];
    #pragma unroll
    for (int rr = 0; rr < R3; ++rr) { acc0[rr] = bd0; acc1[rr] = bd1; }

    for (int k4 = 0; k4 < 20; ++k4) {
        const float* wrow = Wd + (size_t)k4 * 4 * OUTD;
        float w00 = wrow[c],            w01 = wrow[c + 256];
        float w10 = wrow[OUTD + c],     w11 = wrow[OUTD + c + 256];
        float w20 = wrow[2*OUTD + c],   w21 = wrow[2*OUTD + c + 256];
        float w30 = wrow[3*OUTD + c],   w31 = wrow[3*OUTD + c + 256];
        #pragma unroll
        for (int rr = 0; rr < R3; ++rr) {
            float4 a = *(const float4*)&At[rr][k4 * 4];  // broadcast b128
            acc0[rr] = fmaf(a.x, w00, acc0[rr]);
            acc0[rr] = fmaf(a.y, w10, acc0[rr]);
            acc0[rr] = fmaf(a.z, w20, acc0[rr]);
            acc0[rr] = fmaf(a.w, w30, acc0[rr]);
            acc1[rr] = fmaf(a.x, w01, acc1[rr]);
            acc1[rr] = fmaf(a.y, w11, acc1[rr]);
            acc1[rr] = fmaf(a.z, w21, acc1[rr]);
            acc1[rr] = fmaf(a.w, w31, acc1[rr]);
        }
    }

    // LayerNorm over 512 per row: wave-reduce then cross-wave via LDS
    const int wave = tid >> 6, lane = tid & 63;
    #pragma unroll
    for (int rr = 0; rr < R3; ++rr) {
        float s1 = acc0[rr] + acc1[rr];
        float s2 = acc0[rr] * acc0[rr] + acc1[rr] * acc1[rr];
        #pragma unroll
        for (int off = 32; off; off >>= 1) {
            s1 += __shfl_xor(s1, off, 64);
            s2 += __shfl_xor(s2, off, 64);
        }
        if (lane == 0) { s_red[rr][wave][0] = s1; s_red[rr][wave][1] = s2; }
    }
    __syncthreads();

    const float g0 = g_check[c],       g1 = g_check[c + 256];
    const float c0 = b_check[c],       c1 = b_check[c + 256];
    #pragma unroll
    for (int rr = 0; rr < R3; ++rr) {
        float s1 = s_red[rr][0][0] + s_red[rr][1][0] + s_red[rr][2][0] + s_red[rr][3][0];
        float s2 = s_red[rr][0][1] + s_red[rr][1][1] + s_red[rr][2][1] + s_red[rr][3][1];
        float m   = s1 * (1.f / 512.f);
        float var = s2 * (1.f / 512.f) - m * m;
        float inv = rsqrtf(var + LNEPS);
        size_t pairidx = 2 * (size_t)blockIdx.x + (rr >> 4);   // t*32+b
        int tt = (int)(pairidx >> 5), bb2 = (int)(pairidx & 31);
        size_t orow = (size_t)bb2 * SS + (size_t)tt * CURD + (rr & 15);
        out[orow * OUTD + c]       = (acc0[rr] - m) * inv * g0 + c0;
        out[orow * OUTD + c + 256] = (acc1[rr] - m) * inv * g1 + c1;
    }
}

// ---------------------------------------------------------------------------
extern "C" void kernel_launch(void* const* d_in, const int* in_sizes, int n_in,
                              void* d_out, int out_size, void* d_ws, size_t ws_size,
                              hipStream_t stream)
{
    const int*   x       = (const int*)  d_in[0];
    const float* emb     = (const float*)d_in[1];
    const float* Wq      = (const float*)d_in[2];
    const float* bq      = (const float*)d_in[3];
    const float* Wk      = (const float*)d_in[4];
    const float* bk      = (const float*)d_in[5];
    const float* Wv      = (const float*)d_in[6];
    const float* bv      = (const float*)d_in[7];
    const float* g_lim   = (const float*)d_in[8];
    const float* b_lim   = (const float*)d_in[9];
    const float* Ws      = (const float*)d_in[10];
    const float* bs      = (const float*)d_in[11];
    const float* g_doubt = (const float*)d_in[12];
    const float* b_doubt = (const float*)d_in[13];
    const float* Wd      = (const float*)d_in[14];
    const float* bd      = (const float*)d_in[15];
    const float* g_check = (const float*)d_in[16];
    const float* b_check = (const float*)d_in[17];

    float* out      = (float*)d_out;
    float* combined = (float*)d_ws;    // [NCH][BB][CURD][KDIM] fp32 = 40 MB

    attn_kernel<<<dim3(NCH * BB), dim3(256), 0, stream>>>(
        x, emb, Wq, bq, Wk, bk, Wv, bv, g_lim, b_lim, combined);

    rec_kernel<<<dim3(BB * CURD), dim3(64), 0, stream>>>(
        Ws, bs, g_doubt, b_doubt, combined);

    out_kernel<<<dim3((NCH * BB * CURD) / R3), dim3(256), 0, stream>>>(
        combined, Wd, bd, g_check, b_check, out);
}

// Round 2
// 656.196 us; speedup vs baseline: 1.0124x; 1.0124x over previous
//
#include <hip/hip_runtime.h>
#include <math.h>

#define VOCN 50257
#define OUTD 512
#define HIDD 64
#define CURD 16
#define BB   32
#define SS   4096
#define NCH  256      // SS / CURD
#define KDIM 80       // HIDD + CURD
#define LNEPS 1e-5f

// ---------------------------------------------------------------------------
// Kernel 1: per (chunk, batch): emb gather -> q,k,v -> softmax attn -> LN
// Writes watch into combined[row][0:16].  8192 blocks x 256 threads.
// ---------------------------------------------------------------------------
__global__ __launch_bounds__(256) void attn_kernel(
    const int* __restrict__ x, const float* __restrict__ emb,
    const float* __restrict__ Wq, const float* __restrict__ bq,
    const float* __restrict__ Wk, const float* __restrict__ bk,
    const float* __restrict__ Wv, const float* __restrict__ bv,
    const float* __restrict__ g_lim, const float* __restrict__ b_lim,
    float* __restrict__ combined)
{
    const int blk = blockIdx.x;          // t*32 + b
    const int t   = blk >> 5;
    const int b   = blk & 31;
    const int tid = threadIdx.x;
    const int i   = tid >> 4;            // 0..15 row
    const int j   = tid & 15;            // 0..15 col

    __shared__ int   s_ids[16];
    __shared__ float s_wq[16][16], s_wk[16][16], s_wv[16][16];
    __shared__ float s_read[16][17];
    __shared__ float s_q[16][17], s_k[16][17], s_v[16][17], s_p[16][17];

    if (tid < 16) s_ids[tid] = x[b * SS + t * CURD + tid];
    s_wq[i][j] = Wq[tid];
    s_wk[i][j] = Wk[tid];
    s_wv[i][j] = Wv[tid];
    __syncthreads();

    s_read[i][j] = emb[(size_t)s_ids[i] * CURD + j];
    __syncthreads();

    float q = bq[j], k = bk[j], v = bv[j];
    #pragma unroll
    for (int kk = 0; kk < 16; ++kk) {
        float r = s_read[i][kk];
        q = fmaf(r, s_wq[kk][j], q);
        k = fmaf(r, s_wk[kk][j], k);
        v = fmaf(r, s_wv[kk][j], v);
    }
    s_q[i][j] = q; s_k[i][j] = k; s_v[i][j] = v;
    __syncthreads();

    float sc = 0.f;
    #pragma unroll
    for (int kk = 0; kk < 16; ++kk) sc = fmaf(s_q[i][kk], s_k[j][kk], sc);
    sc *= 0.25f;

    float mx = sc;
    #pragma unroll
    for (int off = 8; off; off >>= 1) mx = fmaxf(mx, __shfl_xor(mx, off, 16));
    float p = expf(sc - mx);
    float ps = p;
    #pragma unroll
    for (int off = 8; off; off >>= 1) ps += __shfl_xor(ps, off, 16);
    p /= ps;
    s_p[i][j] = p;
    __syncthreads();

    float w = 0.f;
    #pragma unroll
    for (int kk = 0; kk < 16; ++kk) w = fmaf(s_p[i][kk], s_v[kk][j], w);

    float m = w;
    #pragma unroll
    for (int off = 8; off; off >>= 1) m += __shfl_xor(m, off, 16);
    m *= (1.f / 16.f);
    float d = w - m;
    float var = d * d;
    #pragma unroll
    for (int off = 8; off; off >>= 1) var += __shfl_xor(var, off, 16);
    var *= (1.f / 16.f);
    float wn = d * rsqrtf(var + LNEPS) * g_lim[j] + b_lim[j];

    combined[((size_t)blk * CURD + i) * KDIM + j] = wn;
}

// ---------------------------------------------------------------------------
// Kernel 2: 512 independent chains (b, r), ONE WAVE per chain, NO BARRIERS.
// Single-wave block: DS ops are program-ordered within the wave, so the
// double-buffered s_sus needs no __syncthreads (removes the per-iteration
// vmcnt(0)+lgkmcnt(0) drain of the global store/prefetch).
// watch broadcasts use __shfl (v_readlane) — no memory latency.
// ---------------------------------------------------------------------------
__global__ __launch_bounds__(64) void rec_kernel(
    const float* __restrict__ Ws, const float* __restrict__ bs,
    const float* __restrict__ g_doubt, const float* __restrict__ b_doubt,
    float* __restrict__ combined)
{
    const int chain = blockIdx.x;       // b*16 + r
    const int b = chain >> 4;
    const int r = chain & 15;
    const int c = threadIdx.x;          // 0..63

    __shared__ float s_sus[2][64];

    float Wsw[16], Wss[64];
    #pragma unroll
    for (int jj = 0; jj < 16; ++jj) Wsw[jj] = Ws[jj * HIDD + c];
    #pragma unroll
    for (int jj = 0; jj < 64; ++jj) Wss[jj] = Ws[(16 + jj) * HIDD + c];
    const float bsc = bs[c];
    const float gd  = g_doubt[c];
    const float bdo = b_doubt[c];

    float sv = 0.f;                 // my sus element (state entering chunk t)
    s_sus[0][c] = 0.f;
    int p = 0;

    float wv = (c < 16) ? combined[(((size_t)0 * BB + b) * CURD + r) * KDIM + c] : 0.f;

    for (int t = 0; t < NCH; ++t) {
        const size_t rowoff = (((size_t)t * BB + b) * CURD + r) * (size_t)KDIM;

        // store pre-update state for kernel 3 (fire-and-forget)
        combined[rowoff + 16 + c] = sv;

        // prefetch next chunk's watch row
        float wv_next = 0.f;
        if (t + 1 < NCH && c < 16)
            wv_next = combined[(((size_t)(t + 1) * BB + b) * CURD + r) * KDIM + c];

        // h = bs + watch @ Ws[0:16] + sus @ Ws[16:80]
        float h0 = bsc, h1 = 0.f, h2 = 0.f, h3 = 0.f;
        #pragma unroll
        for (int jj = 0; jj < 16; jj += 4) {
            h0 = fmaf(__shfl(wv, jj + 0, 64), Wsw[jj + 0], h0);
            h1 = fmaf(__shfl(wv, jj + 1, 64), Wsw[jj + 1], h1);
            h2 = fmaf(__shfl(wv, jj + 2, 64), Wsw[jj + 2], h2);
            h3 = fmaf(__shfl(wv, jj + 3, 64), Wsw[jj + 3], h3);
        }
        const float4* sp = (const float4*)(&s_sus[p][0]);
        #pragma unroll
        for (int j4 = 0; j4 < 16; ++j4) {
            float4 a = sp[j4];
            h0 = fmaf(a.x, Wss[4*j4+0], h0);
            h1 = fmaf(a.y, Wss[4*j4+1], h1);
            h2 = fmaf(a.z, Wss[4*j4+2], h2);
            h3 = fmaf(a.w, Wss[4*j4+3], h3);
        }
        float h = (h0 + h1) + (h2 + h3);

        float g = 0.5f * h * (1.f + erff(h * 0.70710678118654752f));

        float s1 = g, s2 = g * g;
        #pragma unroll
        for (int off = 32; off; off >>= 1) {
            s1 += __shfl_xor(s1, off, 64);
            s2 += __shfl_xor(s2, off, 64);
        }
        float m   = s1 * (1.f / 64.f);
        float var = s2 * (1.f / 64.f) - m * m;
        sv = (g - m) * rsqrtf(var + LNEPS) * gd + bdo;

        s_sus[1 - p][c] = sv;    // in-order DS: next iter's reads see this
        p ^= 1;
        wv = wv_next;
    }
}

// ---------------------------------------------------------------------------
// Kernel 3: out = LN(combined @ Wd + bd) * g_check + b_check
// M=131072, K=80, N=512.  Block: 32 rows x 512 cols, 256 threads.
// Thread = (wave rg) x (lane cg): 8 rows x 8 contiguous cols, 64 accs.
// A-reads: wave-uniform ds_read_b128 broadcasts, 160/thread (was 640).
// Each wave owns full 512-col rows -> LN is pure in-wave shuffle reduce.
// ---------------------------------------------------------------------------
#define R3 32
__global__ __launch_bounds__(256, 4) void out_kernel(
    const float* __restrict__ combined, const float* __restrict__ Wd,
    const float* __restrict__ bd, const float* __restrict__ g_check,
    const float* __restrict__ b_check, float* __restrict__ out)
{
    __shared__ float At[R3][84];        // 336B rows = 21*16B -> b128-aligned

    const int tid  = threadIdx.x;
    const int lane = tid & 63;          // col group: cols lane*8 .. +7
    const int rg   = tid >> 6;          // wave idx = row group: rows rg*8..+7
    const size_t rowbase = (size_t)blockIdx.x * R3;

    // stage 32x80 A-tile (rows 320B -> float4-clean)
    const float4* src4 = (const float4*)(combined + rowbase * KDIM);
    #pragma unroll
    for (int u = 0; u < 3; ++u) {
        int idx = tid + 256 * u;
        if (idx < R3 * 20) {
            float4 vv = src4[idx];
            int rr = idx / 20, kk4 = idx % 20;
            *(float4*)&At[rr][kk4 * 4] = vv;
        }
    }
    __syncthreads();

    const int c0 = lane * 8;
    float acc[8][8];
    #pragma unroll
    for (int rr = 0; rr < 8; ++rr)
        #pragma unroll
        for (int cc = 0; cc < 8; ++cc) acc[rr][cc] = 0.f;

    for (int k4 = 0; k4 < 20; ++k4) {
        const float* wp = Wd + (size_t)(k4 * 4) * OUTD + c0;
        float4 wa[4], wb[4];
        #pragma unroll
        for (int kk = 0; kk < 4; ++kk) {
            wa[kk] = *(const float4*)(wp + kk * OUTD);
            wb[kk] = *(const float4*)(wp + kk * OUTD + 4);
        }
        #pragma unroll
        for (int rr = 0; rr < 8; ++rr) {
            float4 a = *(const float4*)&At[rg * 8 + rr][k4 * 4];  // uniform bcast
            float av[4] = {a.x, a.y, a.z, a.w};
            #pragma unroll
            for (int kk = 0; kk < 4; ++kk) {
                acc[rr][0] = fmaf(av[kk], wa[kk].x, acc[rr][0]);
                acc[rr][1] = fmaf(av[kk], wa[kk].y, acc[rr][1]);
                acc[rr][2] = fmaf(av[kk], wa[kk].z, acc[rr][2]);
                acc[rr][3] = fmaf(av[kk], wa[kk].w, acc[rr][3]);
                acc[rr][4] = fmaf(av[kk], wb[kk].x, acc[rr][4]);
                acc[rr][5] = fmaf(av[kk], wb[kk].y, acc[rr][5]);
                acc[rr][6] = fmaf(av[kk], wb[kk].z, acc[rr][6]);
                acc[rr][7] = fmaf(av[kk], wb[kk].w, acc[rr][7]);
            }
        }
    }

    // epilogue: + bd, LayerNorm over 512 (one wave owns the whole row)
    float4 bda = *(const float4*)(bd + c0);
    float4 bdb = *(const float4*)(bd + c0 + 4);
    float4 ga  = *(const float4*)(g_check + c0);
    float4 gb  = *(const float4*)(g_check + c0 + 4);
    float4 ba  = *(const float4*)(b_check + c0);
    float4 bb  = *(const float4*)(b_check + c0 + 4);
    const float bav[8] = {bda.x, bda.y, bda.z, bda.w, bdb.x, bdb.y, bdb.z, bdb.w};
    const float gav[8] = {ga.x, ga.y, ga.z, ga.w, gb.x, gb.y, gb.z, gb.w};
    const float cav[8] = {ba.x, ba.y, ba.z, ba.w, bb.x, bb.y, bb.z, bb.w};

    #pragma unroll
    for (int rr = 0; rr < 8; ++rr) {
        float s1 = 0.f, s2 = 0.f;
        #pragma unroll
        for (int cc = 0; cc < 8; ++cc) {
            float vv = acc[rr][cc] + bav[cc];
            acc[rr][cc] = vv;
            s1 += vv;
            s2 += vv * vv;
        }
        #pragma unroll
        for (int off = 32; off; off >>= 1) {
            s1 += __shfl_xor(s1, off, 64);
            s2 += __shfl_xor(s2, off, 64);
        }
        float m   = s1 * (1.f / 512.f);
        float var = s2 * (1.f / 512.f) - m * m;
        float inv = rsqrtf(var + LNEPS);

        size_t R = rowbase + (size_t)rg * 8 + rr;       // linear (t,b,i) row
        int ii = (int)(R & 15);
        int bb2 = (int)((R >> 4) & 31);
        int tt = (int)(R >> 9);
        size_t orow = (size_t)bb2 * SS + (size_t)tt * CURD + ii;

        float4 o0, o1;
        o0.x = (acc[rr][0] - m) * inv * gav[0] + cav[0];
        o0.y = (acc[rr][1] - m) * inv * gav[1] + cav[1];
        o0.z = (acc[rr][2] - m) * inv * gav[2] + cav[2];
        o0.w = (acc[rr][3] - m) * inv * gav[3] + cav[3];
        o1.x = (acc[rr][4] - m) * inv * gav[4] + cav[4];
        o1.y = (acc[rr][5] - m) * inv * gav[5] + cav[5];
        o1.z = (acc[rr][6] - m) * inv * gav[6] + cav[6];
        o1.w = (acc[rr][7] - m) * inv * gav[7] + cav[7];
        *(float4*)(out + orow * OUTD + c0)     = o0;
        *(float4*)(out + orow * OUTD + c0 + 4) = o1;
    }
}

// ---------------------------------------------------------------------------
extern "C" void kernel_launch(void* const* d_in, const int* in_sizes, int n_in,
                              void* d_out, int out_size, void* d_ws, size_t ws_size,
                              hipStream_t stream)
{
    const int*   x       = (const int*)  d_in[0];
    const float* emb     = (const float*)d_in[1];
    const float* Wq      = (const float*)d_in[2];
    const float* bq      = (const float*)d_in[3];
    const float* Wk      = (const float*)d_in[4];
    const float* bk      = (const float*)d_in[5];
    const float* Wv      = (const float*)d_in[6];
    const float* bv      = (const float*)d_in[7];
    const float* g_lim   = (const float*)d_in[8];
    const float* b_lim   = (const float*)d_in[9];
    const float* Ws      = (const float*)d_in[10];
    const float* bs      = (const float*)d_in[11];
    const float* g_doubt = (const float*)d_in[12];
    const float* b_doubt = (const float*)d_in[13];
    const float* Wd      = (const float*)d_in[14];
    const float* bd      = (const float*)d_in[15];
    const float* g_check = (const float*)d_in[16];
    const float* b_check = (const float*)d_in[17];

    float* out      = (float*)d_out;
    float* combined = (float*)d_ws;    // [NCH][BB][CURD][KDIM] fp32 = 40 MB

    attn_kernel<<<dim3(NCH * BB), dim3(256), 0, stream>>>(
        x, emb, Wq, bq, Wk, bk, Wv, bv, g_lim, b_lim, combined);

    rec_kernel<<<dim3(BB * CURD), dim3(64), 0, stream>>>(
        Ws, bs, g_doubt, b_doubt, combined);

    out_kernel<<<dim3((NCH * BB * CURD) / R3), dim3(256), 0, stream>>>(
        combined, Wd, bd, g_check, b_check, out);
}

// Round 3
// 575.588 us; speedup vs baseline: 1.1542x; 1.1400x over previous
//
#include <hip/hip_runtime.h>
#include <math.h>

#define VOCN 50257
#define OUTD 512
#define HIDD 64
#define CURD 16
#define BB   32
#define SS   4096
#define NCH  256      // SS / CURD
#define KDIM 80       // HIDD + CURD
#define LNEPS 1e-5f

// ---------------------------------------------------------------------------
// Kernel 1: attention, ONE WAVE per (t,b) tile, no barriers.
// lane = i*4 + jg: row i (0..15), col group jg (cols jg*4..+3).
// Per-wave LDS tiles R(->P),Q,K,V with row stride 20 (bank-friendly).
// All LDS hazards are write->read within the same wave (in-order DS pipe).
// ---------------------------------------------------------------------------
__global__ __launch_bounds__(256) void attn_kernel(
    const int* __restrict__ x, const float* __restrict__ emb,
    const float* __restrict__ Wq, const float* __restrict__ bq,
    const float* __restrict__ Wk, const float* __restrict__ bk,
    const float* __restrict__ Wv, const float* __restrict__ bv,
    const float* __restrict__ g_lim, const float* __restrict__ b_lim,
    float* __restrict__ combined)
{
    const int wid  = threadIdx.x >> 6;         // wave in block
    const int lane = threadIdx.x & 63;
    const int tile = blockIdx.x * 4 + wid;     // t*32 + b
    const int t = tile >> 5, b = tile & 31;
    const int i  = lane >> 2;                  // row 0..15
    const int jg = lane & 3;                   // col group
    const int j0 = jg * 4;

    __shared__ __align__(16) float ldsT[4][4][16][20];
    float (*R)[20] = ldsT[wid][0];             // read tile, later reused as P
    float (*Q)[20] = ldsT[wid][1];
    float (*K)[20] = ldsT[wid][2];
    float (*V)[20] = ldsT[wid][3];

    // token ids: lanes 0..15 load, broadcast to row owners
    int myid = 0;
    if (lane < 16) myid = x[b * SS + t * CURD + lane];
    const int id_i = __shfl(myid, i, 64);

    // embedding read: each lane its own float4 chunk of row i
    float4 r4 = *(const float4*)(emb + (size_t)id_i * CURD + j0);
    *(float4*)&R[i][j0] = r4;

    // full read-row into registers
    float rrow[16];
    {
        float4 t0 = *(const float4*)&R[i][0];
        float4 t1 = *(const float4*)&R[i][4];
        float4 t2 = *(const float4*)&R[i][8];
        float4 t3 = *(const float4*)&R[i][12];
        rrow[0]=t0.x; rrow[1]=t0.y; rrow[2]=t0.z;  rrow[3]=t0.w;
        rrow[4]=t1.x; rrow[5]=t1.y; rrow[6]=t1.z;  rrow[7]=t1.w;
        rrow[8]=t2.x; rrow[9]=t2.y; rrow[10]=t2.z; rrow[11]=t2.w;
        rrow[12]=t3.x; rrow[13]=t3.y; rrow[14]=t3.z; rrow[15]=t3.w;
    }

    // q,k,v for (row i, cols j0..j0+3); weights direct from global (L1/L2-hot)
    float4 q4 = *(const float4*)(bq + j0);
    float4 k4 = *(const float4*)(bk + j0);
    float4 v4 = *(const float4*)(bv + j0);
    #pragma unroll
    for (int k = 0; k < 16; ++k) {
        float rv = rrow[k];
        float4 wq4 = *(const float4*)(Wq + k * CURD + j0);
        float4 wk4 = *(const float4*)(Wk + k * CURD + j0);
        float4 wv4 = *(const float4*)(Wv + k * CURD + j0);
        q4.x = fmaf(rv, wq4.x, q4.x); q4.y = fmaf(rv, wq4.y, q4.y);
        q4.z = fmaf(rv, wq4.z, q4.z); q4.w = fmaf(rv, wq4.w, q4.w);
        k4.x = fmaf(rv, wk4.x, k4.x); k4.y = fmaf(rv, wk4.y, k4.y);
        k4.z = fmaf(rv, wk4.z, k4.z); k4.w = fmaf(rv, wk4.w, k4.w);
        v4.x = fmaf(rv, wv4.x, v4.x); v4.y = fmaf(rv, wv4.y, v4.y);
        v4.z = fmaf(rv, wv4.z, v4.z); v4.w = fmaf(rv, wv4.w, v4.w);
    }
    *(float4*)&Q[i][j0] = q4;
    *(float4*)&K[i][j0] = k4;
    *(float4*)&V[i][j0] = v4;

    // scores: sc[jj] = q_i . k_{j0+jj} * 0.25
    float qrow[16];
    {
        float4 t0 = *(const float4*)&Q[i][0];
        float4 t1 = *(const float4*)&Q[i][4];
        float4 t2 = *(const float4*)&Q[i][8];
        float4 t3 = *(const float4*)&Q[i][12];
        qrow[0]=t0.x; qrow[1]=t0.y; qrow[2]=t0.z;  qrow[3]=t0.w;
        qrow[4]=t1.x; qrow[5]=t1.y; qrow[6]=t1.z;  qrow[7]=t1.w;
        qrow[8]=t2.x; qrow[9]=t2.y; qrow[10]=t2.z; qrow[11]=t2.w;
        qrow[12]=t3.x; qrow[13]=t3.y; qrow[14]=t3.z; qrow[15]=t3.w;
    }
    float sc[4];
    #pragma unroll
    for (int jj = 0; jj < 4; ++jj) {
        const int row = j0 + jj;
        float4 c0 = *(const float4*)&K[row][0];
        float4 c1 = *(const float4*)&K[row][4];
        float4 c2 = *(const float4*)&K[row][8];
        float4 c3 = *(const float4*)&K[row][12];
        float d0 = qrow[0]*c0.x + qrow[1]*c0.y + qrow[2]*c0.z + qrow[3]*c0.w;
        float d1 = qrow[4]*c1.x + qrow[5]*c1.y + qrow[6]*c1.z + qrow[7]*c1.w;
        float d2 = qrow[8]*c2.x + qrow[9]*c2.y + qrow[10]*c2.z + qrow[11]*c2.w;
        float d3 = qrow[12]*c3.x + qrow[13]*c3.y + qrow[14]*c3.z + qrow[15]*c3.w;
        sc[jj] = ((d0 + d1) + (d2 + d3)) * 0.25f;
    }

    // softmax over the 16 cols of row i (4 lanes x 4 vals; lanes i*4..i*4+3)
    float mx = fmaxf(fmaxf(sc[0], sc[1]), fmaxf(sc[2], sc[3]));
    mx = fmaxf(mx, __shfl_xor(mx, 1));
    mx = fmaxf(mx, __shfl_xor(mx, 2));
    float e0 = expf(sc[0]-mx), e1 = expf(sc[1]-mx),
          e2 = expf(sc[2]-mx), e3 = expf(sc[3]-mx);
    float es = (e0 + e1) + (e2 + e3);
    es += __shfl_xor(es, 1);
    es += __shfl_xor(es, 2);
    float rs = 1.f / es;
    float4 p4 = make_float4(e0*rs, e1*rs, e2*rs, e3*rs);
    *(float4*)&R[i][j0] = p4;      // P tile overwrites R (R reads all done)

    // watch[i][j0..+3] = sum_k P[i][k] * V[k][j0..+3]
    float prow[16];
    {
        float4 t0 = *(const float4*)&R[i][0];
        float4 t1 = *(const float4*)&R[i][4];
        float4 t2 = *(const float4*)&R[i][8];
        float4 t3 = *(const float4*)&R[i][12];
        prow[0]=t0.x; prow[1]=t0.y; prow[2]=t0.z;  prow[3]=t0.w;
        prow[4]=t1.x; prow[5]=t1.y; prow[6]=t1.z;  prow[7]=t1.w;
        prow[8]=t2.x; prow[9]=t2.y; prow[10]=t2.z; prow[11]=t2.w;
        prow[12]=t3.x; prow[13]=t3.y; prow[14]=t3.z; prow[15]=t3.w;
    }
    float4 w4 = make_float4(0.f, 0.f, 0.f, 0.f);
    #pragma unroll
    for (int k = 0; k < 16; ++k) {
        float4 vk = *(const float4*)&V[k][j0];
        float pv = prow[k];
        w4.x = fmaf(pv, vk.x, w4.x); w4.y = fmaf(pv, vk.y, w4.y);
        w4.z = fmaf(pv, vk.z, w4.z); w4.w = fmaf(pv, vk.w, w4.w);
    }

    // LayerNorm over 16
    float s1 = (w4.x + w4.y) + (w4.z + w4.w);
    float s2 = (w4.x*w4.x + w4.y*w4.y) + (w4.z*w4.z + w4.w*w4.w);
    s1 += __shfl_xor(s1, 1); s1 += __shfl_xor(s1, 2);
    s2 += __shfl_xor(s2, 1); s2 += __shfl_xor(s2, 2);
    float m   = s1 * (1.f / 16.f);
    float var = s2 * (1.f / 16.f) - m * m;
    float inv = rsqrtf(var + LNEPS);
    float4 gl = *(const float4*)(g_lim + j0);
    float4 bl = *(const float4*)(b_lim + j0);
    float4 o;
    o.x = (w4.x - m) * inv * gl.x + bl.x;
    o.y = (w4.y - m) * inv * gl.y + bl.y;
    o.z = (w4.z - m) * inv * gl.z + bl.z;
    o.w = (w4.w - m) * inv * gl.w + bl.w;
    *(float4*)(combined + ((size_t)tile * CURD + i) * KDIM + j0) = o;
}

// ---------------------------------------------------------------------------
// Kernel 2: 512 chains, one wave each, no barriers. LN algebraically folded:
//   next sus-part = inv*(P - m*u) + w0,  P = sum_j G_j * (gd_j*Ws[16+j][c])
// so the LDS matvec starts straight from gelu output G; the shfl reduce for
// (m, inv) runs concurrently and merges at the end with 2 FMAs.
// ---------------------------------------------------------------------------
__global__ __launch_bounds__(64) void rec_kernel(
    const float* __restrict__ Ws, const float* __restrict__ bs,
    const float* __restrict__ g_doubt, const float* __restrict__ b_doubt,
    float* __restrict__ combined)
{
    const int chain = blockIdx.x;       // b*16 + r
    const int b = chain >> 4;
    const int r = chain & 15;
    const int c = threadIdx.x;          // 0..63

    __shared__ __align__(16) float s_G[64];
    __shared__ __align__(16) float s_watch[16];

    float Wsw[16];
    #pragma unroll
    for (int j = 0; j < 16; ++j) Wsw[j] = Ws[j * HIDD + c];

    float Wsp[64];
    float u = 0.f, w0 = 0.f;
    #pragma unroll
    for (int j = 0; j < 64; ++j) {
        float w   = Ws[(16 + j) * HIDD + c];
        float gdj = g_doubt[j];
        float bdj = b_doubt[j];
        Wsp[j] = gdj * w;
        u += Wsp[j];
        w0 = fmaf(bdj, w, w0);
    }
    const float bsc  = bs[c];
    const float gd_c = g_doubt[c];
    const float bd_c = b_doubt[c];

    float P = 0.f, mp = 0.f, ip = 0.f, w0f = 0.f;
    float sv_store = 0.f;               // sus entering current t
    float wv = (c < 16) ? combined[((size_t)b * CURD + r) * KDIM + c] : 0.f;

    size_t rowoff = ((size_t)b * CURD + r) * KDIM;          // t = 0
    const size_t stride = (size_t)BB * CURD * KDIM;

    for (int t = 0; t < NCH; ++t) {
        combined[rowoff + 16 + c] = sv_store;   // fire-and-forget
        if (c < 16) s_watch[c] = wv;
        float wv_next = 0.f;
        if (t + 1 < NCH && c < 16) wv_next = combined[rowoff + stride + c];

        // h = bs + sus-part + watch-part
        float h0 = fmaf(ip, P - mp * u, bsc + w0f);
        float h1 = 0.f, h2 = 0.f, h3 = 0.f;
        {
            const float4* wp4 = (const float4*)s_watch;
            float4 a0 = wp4[0], a1 = wp4[1], a2 = wp4[2], a3 = wp4[3];
            h0 = fmaf(a0.x, Wsw[0],  h0); h1 = fmaf(a0.y, Wsw[1],  h1);
            h2 = fmaf(a0.z, Wsw[2],  h2); h3 = fmaf(a0.w, Wsw[3],  h3);
            h0 = fmaf(a1.x, Wsw[4],  h0); h1 = fmaf(a1.y, Wsw[5],  h1);
            h2 = fmaf(a1.z, Wsw[6],  h2); h3 = fmaf(a1.w, Wsw[7],  h3);
            h0 = fmaf(a2.x, Wsw[8],  h0); h1 = fmaf(a2.y, Wsw[9],  h1);
            h2 = fmaf(a2.z, Wsw[10], h2); h3 = fmaf(a2.w, Wsw[11], h3);
            h0 = fmaf(a3.x, Wsw[12], h0); h1 = fmaf(a3.y, Wsw[13], h1);
            h2 = fmaf(a3.z, Wsw[14], h2); h3 = fmaf(a3.w, Wsw[15], h3);
        }
        float h = (h0 + h1) + (h2 + h3);

        // exact gelu
        float G = 0.5f * h * (1.f + erff(h * 0.70710678118654752f));

        // start the LDS round-trip immediately
        s_G[c] = G;
        const float4* gp = (const float4*)s_G;
        float4 xr[16];
        #pragma unroll
        for (int j4 = 0; j4 < 16; ++j4) xr[j4] = gp[j4];

        // reduce (m, inv) — overlaps with the LDS reads above
        float s1 = G, s2 = G * G;
        #pragma unroll
        for (int off = 32; off; off >>= 1) {
            s1 += __shfl_xor(s1, off, 64);
            s2 += __shfl_xor(s2, off, 64);
        }
        float m   = s1 * (1.f / 64.f);
        float var = s2 * (1.f / 64.f) - m * m;
        float inv = rsqrtf(var + LNEPS);

        // P = sum_j G_j * Wsp_j   (8 accumulators)
        float p0=0.f,p1=0.f,p2=0.f,p3=0.f,p4=0.f,p5=0.f,p6=0.f,p7=0.f;
        #pragma unroll
        for (int j4 = 0; j4 < 16; j4 += 2) {
            float4 x0 = xr[j4], x1 = xr[j4 + 1];
            p0 = fmaf(x0.x, Wsp[4*j4+0], p0);
            p1 = fmaf(x0.y, Wsp[4*j4+1], p1);
            p2 = fmaf(x0.z, Wsp[4*j4+2], p2);
            p3 = fmaf(x0.w, Wsp[4*j4+3], p3);
            p4 = fmaf(x1.x, Wsp[4*j4+4], p4);
            p5 = fmaf(x1.y, Wsp[4*j4+5], p5);
            p6 = fmaf(x1.z, Wsp[4*j4+6], p6);
            p7 = fmaf(x1.w, Wsp[4*j4+7], p7);
        }
        P = ((p0 + p1) + (p2 + p3)) + ((p4 + p5) + (p6 + p7));

        // state for next iteration
        sv_store = fmaf((G - m) * inv, gd_c, bd_c);
        mp = m; ip = inv; w0f = w0;
        wv = wv_next;
        rowoff += stride;
    }
}

// ---------------------------------------------------------------------------
// Kernel 3: out = LN(combined @ Wd + bd) * g_check + b_check
// 32 rows x 512 cols per block, 256 threads; wave=8 rows, lane=8 cols.
// No min-wave bound: let the allocator keep all 64 accs + weights in VGPRs.
// ---------------------------------------------------------------------------
#define R3 32
__global__ __launch_bounds__(256) void out_kernel(
    const float* __restrict__ combined, const float* __restrict__ Wd,
    const float* __restrict__ bd, const float* __restrict__ g_check,
    const float* __restrict__ b_check, float* __restrict__ out)
{
    __shared__ float At[R3][84];        // 336B rows -> b128-aligned

    const int tid  = threadIdx.x;
    const int lane = tid & 63;          // col group: cols lane*8 .. +7
    const int rg   = tid >> 6;          // wave idx = row group: rows rg*8..+7
    const size_t rowbase = (size_t)blockIdx.x * R3;

    const float4* src4 = (const float4*)(combined + rowbase * KDIM);
    #pragma unroll
    for (int u = 0; u < 3; ++u) {
        int idx = tid + 256 * u;
        if (idx < R3 * 20) {
            float4 vv = src4[idx];
            int rr = idx / 20, kk4 = idx % 20;
            *(float4*)&At[rr][kk4 * 4] = vv;
        }
    }
    __syncthreads();

    const int c0 = lane * 8;
    float acc[8][8];
    #pragma unroll
    for (int rr = 0; rr < 8; ++rr)
        #pragma unroll
        for (int cc = 0; cc < 8; ++cc) acc[rr][cc] = 0.f;

    for (int k4 = 0; k4 < 20; ++k4) {
        const float* wp = Wd + (size_t)(k4 * 4) * OUTD + c0;
        float4 wa[4], wb[4];
        #pragma unroll
        for (int kk = 0; kk < 4; ++kk) {
            wa[kk] = *(const float4*)(wp + kk * OUTD);
            wb[kk] = *(const float4*)(wp + kk * OUTD + 4);
        }
        #pragma unroll
        for (int rr = 0; rr < 8; ++rr) {
            float4 a = *(const float4*)&At[rg * 8 + rr][k4 * 4];  // uniform bcast
            float av[4] = {a.x, a.y, a.z, a.w};
            #pragma unroll
            for (int kk = 0; kk < 4; ++kk) {
                acc[rr][0] = fmaf(av[kk], wa[kk].x, acc[rr][0]);
                acc[rr][1] = fmaf(av[kk], wa[kk].y, acc[rr][1]);
                acc[rr][2] = fmaf(av[kk], wa[kk].z, acc[rr][2]);
                acc[rr][3] = fmaf(av[kk], wa[kk].w, acc[rr][3]);
                acc[rr][4] = fmaf(av[kk], wb[kk].x, acc[rr][4]);
                acc[rr][5] = fmaf(av[kk], wb[kk].y, acc[rr][5]);
                acc[rr][6] = fmaf(av[kk], wb[kk].z, acc[rr][6]);
                acc[rr][7] = fmaf(av[kk], wb[kk].w, acc[rr][7]);
            }
        }
    }

    float4 bda = *(const float4*)(bd + c0);
    float4 bdb = *(const float4*)(bd + c0 + 4);
    float4 ga  = *(const float4*)(g_check + c0);
    float4 gb  = *(const float4*)(g_check + c0 + 4);
    float4 ba  = *(const float4*)(b_check + c0);
    float4 bb  = *(const float4*)(b_check + c0 + 4);
    const float bav[8] = {bda.x, bda.y, bda.z, bda.w, bdb.x, bdb.y, bdb.z, bdb.w};
    const float gav[8] = {ga.x, ga.y, ga.z, ga.w, gb.x, gb.y, gb.z, gb.w};
    const float cav[8] = {ba.x, ba.y, ba.z, ba.w, bb.x, bb.y, bb.z, bb.w};

    #pragma unroll
    for (int rr = 0; rr < 8; ++rr) {
        float s1 = 0.f, s2 = 0.f;
        #pragma unroll
        for (int cc = 0; cc < 8; ++cc) {
            float vv = acc[rr][cc] + bav[cc];
            acc[rr][cc] = vv;
            s1 += vv;
            s2 += vv * vv;
        }
        #pragma unroll
        for (int off = 32; off; off >>= 1) {
            s1 += __shfl_xor(s1, off, 64);
            s2 += __shfl_xor(s2, off, 64);
        }
        float m   = s1 * (1.f / 512.f);
        float var = s2 * (1.f / 512.f) - m * m;
        float inv = rsqrtf(var + LNEPS);

        size_t R = rowbase + (size_t)rg * 8 + rr;
        int ii  = (int)(R & 15);
        int bb2 = (int)((R >> 4) & 31);
        int tt  = (int)(R >> 9);
        size_t orow = (size_t)bb2 * SS + (size_t)tt * CURD + ii;

        float4 o0, o1;
        o0.x = (acc[rr][0] - m) * inv * gav[0] + cav[0];
        o0.y = (acc[rr][1] - m) * inv * gav[1] + cav[1];
        o0.z = (acc[rr][2] - m) * inv * gav[2] + cav[2];
        o0.w = (acc[rr][3] - m) * inv * gav[3] + cav[3];
        o1.x = (acc[rr][4] - m) * inv * gav[4] + cav[4];
        o1.y = (acc[rr][5] - m) * inv * gav[5] + cav[5];
        o1.z = (acc[rr][6] - m) * inv * gav[6] + cav[6];
        o1.w = (acc[rr][7] - m) * inv * gav[7] + cav[7];
        *(float4*)(out + orow * OUTD + c0)     = o0;
        *(float4*)(out + orow * OUTD + c0 + 4) = o1;
    }
}

// ---------------------------------------------------------------------------
extern "C" void kernel_launch(void* const* d_in, const int* in_sizes, int n_in,
                              void* d_out, int out_size, void* d_ws, size_t ws_size,
                              hipStream_t stream)
{
    const int*   x       = (const int*)  d_in[0];
    const float* emb     = (const float*)d_in[1];
    const float* Wq      = (const float*)d_in[2];
    const float* bq      = (const float*)d_in[3];
    const float* Wk      = (const float*)d_in[4];
    const float* bk      = (const float*)d_in[5];
    const float* Wv      = (const float*)d_in[6];
    const float* bv      = (const float*)d_in[7];
    const float* g_lim   = (const float*)d_in[8];
    const float* b_lim   = (const float*)d_in[9];
    const float* Ws      = (const float*)d_in[10];
    const float* bs      = (const float*)d_in[11];
    const float* g_doubt = (const float*)d_in[12];
    const float* b_doubt = (const float*)d_in[13];
    const float* Wd      = (const float*)d_in[14];
    const float* bd      = (const float*)d_in[15];
    const float* g_check = (const float*)d_in[16];
    const float* b_check = (const float*)d_in[17];

    float* out      = (float*)d_out;
    float* combined = (float*)d_ws;    // [NCH][BB][CURD][KDIM] fp32 = 40 MB

    attn_kernel<<<dim3(NCH * BB / 4), dim3(256), 0, stream>>>(
        x, emb, Wq, bq, Wk, bk, Wv, bv, g_lim, b_lim, combined);

    rec_kernel<<<dim3(BB * CURD), dim3(64), 0, stream>>>(
        Ws, bs, g_doubt, b_doubt, combined);

    out_kernel<<<dim3((NCH * BB * CURD) / R3), dim3(256), 0, stream>>>(
        combined, Wd, bd, g_check, b_check, out);
}